// Round 11
// baseline (223.039 us; speedup 1.0000x reference)
//
#include <hip/hip_runtime.h>

// GRU: B=8192 chains, T=512 steps, IN=5, H=7, fused heads.
// R13 = R12 (114us, VALUBusy 64%) attacking the ~200cy/step unmodeled stall.
// Evidence: wall 534cy/step-SIMD, issue 171cy; VGPR=60 == exact ledger of a
// COLLAPSED x double-buffer (20 xbuf + 10 stage + ~32 weights) -> every
// 4-step chunk eats raw ds_read latency. And the 32-step unrolled tile body
// (~20KB x 2 blocks/CU) overflows 32KB L1I -> I-fetch streaming.
// Changes vs R12 (data path & math BIT-IDENTICAL):
//  (1) chunk loop DYNAMIC (4 iters x 8 steps): tile body ~4KB, fits L1I.
//      Per-step head-store guard deleted: flush guards already skip the
//      tl=0 slot-0 outputs exactly (ring slot 0 holds head(h_init), never
//      stored). Ring/x addressing via incremented pointers + imm offsets.
//  (2) ENFORCED x double-buffer: two named float[20] arrays (static
//      indexing only -> SROA to regs), chunk loads issued at half-body top,
//      sched_barrier(0) pins them above the compute so the scheduler
//      cannot re-sink them. Compiler still inserts the minimal lgkmcnt.
//  (3) masked-DPP rv/zv: update_dpp(old=s, src=s, ror:8, bank_mask) -- one
//      instr each replaces sv-dpp + 2 cndmask, and shortens the r->n chain.
// R12 (verified): no barrier (all LDS group-private within a wave);
// head ring HSTR=136 planes 0/34/68/102. R10 (verified): ds_write2 ring +
// coalesced per-tile flush. R9 (verified): gate pre-scaling (-log2e / 
// -2log2e). R7 (verified): heads ride pad lanes l=7,15; head of h_{s-1}
// surfaces at step s -> index s-1; epilogue does 511.
// Layout (R4/R5): 16 lanes/batch; slot0 = r row (l<8) / z row (l>=8),
// slot1 = n row; one sigmoid/lane + ror:8 half-swap.
// DPP anchor (R3-R12 passed): row_ror:N dst[n]=src[(n-N)mod16].

namespace {
constexpr int Bn = 8192;
constexpr int Tn = 512;
constexpr int INn = 5;
constexpr int Hn = 7;
constexpr int TILE = 32;
constexpr int NTILE = Tn / TILE;         // 16
constexpr int BPB = 16;                  // batches per block (256 thr / 16)
constexpr int XSTR = 164;                // padded floats/batch in LDS (x)
constexpr int HSTR = 136;                // head ring: m0@0,m1@34,m2@68,r@102
constexpr long long OFF_OR = (long long)Bn * Tn * 3;
constexpr long long OFF_HL = OFF_OR + (long long)Bn * Tn;
constexpr float LOG2E = 1.44269504088896340736f;
}

typedef float v2f __attribute__((ext_vector_type(2)));

__device__ __forceinline__ v2f pk_fma(v2f a, v2f b, v2f c) {
    return __builtin_elementwise_fma(a, b, c);
}
__device__ __forceinline__ v2f splat2(float x) { return (v2f){x, x}; }

template<int CTRL>
__device__ __forceinline__ float dppf(float v) {
    int r = __builtin_amdgcn_update_dpp(0, __builtin_bit_cast(int, v),
                                        CTRL, 0xF, 0xF, true);
    return __builtin_bit_cast(float, r);
}
// masked DPP: lanes in enabled banks get ror:8(src); others keep old.
template<int BANK>
__device__ __forceinline__ float dpp_ror8_m(float old_, float v) {
    int r = __builtin_amdgcn_update_dpp(__builtin_bit_cast(int, old_),
                                        __builtin_bit_cast(int, v),
                                        0x128, 0xF, BANK, false);
    return __builtin_bit_cast(float, r);
}

__global__ __launch_bounds__(256, 2) void gru_fused_kernel(
    const float* __restrict__ x,     // [B, T, IN]
    const float* __restrict__ W_ih,  // [21, 5]
    const float* __restrict__ W_hh,  // [21, 7]
    const float* __restrict__ b_ih,  // [21]
    const float* __restrict__ b_hh,  // [21]
    const float* __restrict__ W_h0,  // [7, 1]
    const float* __restrict__ W_m,   // [3, 7]
    const float* __restrict__ b_m,   // [3]
    const float* __restrict__ W_r,   // [1, 7]
    const float* __restrict__ b_r,   // [1]
    float* __restrict__ out)
{
    __shared__ float lds_x[2][BPB * XSTR];   // 2 x 10.25 KB
    __shared__ float lds_h[BPB * HSTR];      // 8.5 KB head ring

    const int tid  = threadIdx.x;
    const int l    = tid & 15;           // lane within 16-lane batch group
    const int j    = l & 7;              // hidden-unit slot (7 = pad/head lane)
    const int g    = tid >> 4;           // batch slot in block
    const int b    = blockIdx.x * BPB + g;
    const int jj   = (j < 7) ? j : 6;
    const bool lo8 = ((l & 8) == 0);
    const bool hl  = (j == 7);           // head lanes: l == 7 and l == 15
    const bool is15 = hl && !lo8;        // lane 15

    const float kR = -LOG2E;             // slot0 scale (sigmoid preact)
    const float kN = -2.0f * LOG2E;      // slot1 scale (tanh preact)

    // ---- rotated, packed weights (R7/R9, verified) ----
    const int row0 = lo8 ? jj : (Hn + jj);
    const int row1 = 2 * Hn + jj;

    v2f whh_rot[8];
    #pragma unroll
    for (int i = 0; i < 8; ++i) {
        const int k = (j - i) & 7;
        if (k < 7) {
            if (hl) {
                const float w0 = lo8 ? W_m[0 * Hn + k] : W_m[2 * Hn + k];
                const float w1 = lo8 ? W_m[1 * Hn + k] : W_r[k];
                whh_rot[i] = (v2f){w0, w1};
            } else {
                whh_rot[i] = (v2f){kR * W_hh[row0 * Hn + k],
                                   kN * W_hh[row1 * Hn + k]};
            }
        } else {
            whh_rot[i] = (v2f){0.0f, 0.0f};
        }
    }
    v2f wih01[INn];
    #pragma unroll
    for (int i = 0; i < INn; ++i)
        wih01[i] = hl ? (v2f){0.0f, 0.0f}
                      : (v2f){kR * W_ih[row0 * INn + i],
                              kN * W_ih[row1 * INn + i]};
    const v2f biasH = hl ? (lo8 ? (v2f){b_m[0], b_m[1]}
                                : (v2f){b_m[2], b_r[0]})
                         : (v2f){kR * b_hh[row0], kN * b_hh[row1]};
    const v2f biasP = hl ? (v2f){0.0f, 0.0f}
                         : (v2f){kR * b_ih[row0], kN * b_ih[row1]};

    float hj = W_h0[jj];

    const float* xb = x + (long long)b * (Tn * INn);
    float* om  = out + (long long)b * (Tn * 3);
    float* orr = out + OFF_OR + (long long)b * Tn;

    // head ring bases + flush read offsets (tile-invariant)
    float* hwb = &lds_h[g * HSTR + (is15 ? 68 : 0)];   // writer (lanes 7/15)
    const float* hrd = &lds_h[g * HSTR];               // flush reader
    int fq[6];
    #pragma unroll
    for (int i = 0; i < 6; ++i) {
        const int q = i * 16 + l;                      // output dword 0..95
        fq[i] = (q % 3) * 34 + q / 3;                  // planar -> interleaved
    }

    // one GRU step; SS compile-time (0..3), xarr statically indexed,
    // hw = ring pointer for this 4-step subchunk (imm dword offsets)
    #define GRU_STEP(xarr, SS, hw)                                        \
    {                                                                     \
        v2f accA = biasH;                                                 \
        v2f accB = (v2f){0.0f, 0.0f};                                     \
        accA = pk_fma(whh_rot[0], splat2(hj), accA);                      \
        float h1 = dppf<0x121>(hj);                                       \
        accB = pk_fma(whh_rot[1], splat2(h1), accB);                      \
        float h2 = dppf<0x122>(hj);                                       \
        accA = pk_fma(whh_rot[2], splat2(h2), accA);                      \
        float h3 = dppf<0x123>(hj);                                       \
        accB = pk_fma(whh_rot[3], splat2(h3), accB);                      \
        float h4 = dppf<0x124>(hj);                                       \
        accA = pk_fma(whh_rot[4], splat2(h4), accA);                      \
        float h5 = dppf<0x125>(hj);                                       \
        accB = pk_fma(whh_rot[5], splat2(h5), accB);                      \
        float h6 = dppf<0x126>(hj);                                       \
        accA = pk_fma(whh_rot[6], splat2(h6), accA);                      \
        float h7 = dppf<0x127>(hj);                                       \
        accB = pk_fma(whh_rot[7], splat2(h7), accB);                      \
        v2f accH = accA + accB;                                           \
        v2f accP = biasP;                                                 \
        accP = pk_fma(wih01[0], splat2((xarr)[5*(SS)+0]), accP);          \
        accP = pk_fma(wih01[1], splat2((xarr)[5*(SS)+1]), accP);          \
        accP = pk_fma(wih01[2], splat2((xarr)[5*(SS)+2]), accP);          \
        accP = pk_fma(wih01[3], splat2((xarr)[5*(SS)+3]), accP);          \
        accP = pk_fma(wih01[4], splat2((xarr)[5*(SS)+4]), accP);          \
        if (hl) {                                                         \
            (hw)[(SS)]      = accH[0];                                    \
            (hw)[34 + (SS)] = accH[1];                                    \
        }                                                                 \
        float ea = __builtin_amdgcn_exp2f(accH[0] + accP[0]);             \
        float s  = __builtin_amdgcn_rcpf(1.0f + ea);                      \
        float rv = dpp_ror8_m<0xC>(s, s);  /* hi8 <- lo half's r */       \
        float zv = dpp_ror8_m<0x3>(s, s);  /* lo8 <- hi half's z */       \
        float et = __builtin_amdgcn_exp2f(fmaf(rv, accH[1], accP[1]));    \
        float t  = __builtin_amdgcn_rcpf(1.0f + et);                      \
        float n  = fmaf(2.0f, t, -1.0f);                                  \
        hj = n + zv * (hj - n);                                           \
    }

    // loads 1 chunk (4 steps = 20 floats) LDS -> named float array (SROA)
    #define LOADX(dst, p)                                                 \
    {                                                                     \
        float4 t0_ = (p)[0], t1_ = (p)[1], t2_ = (p)[2],                  \
               t3_ = (p)[3], t4_ = (p)[4];                                \
        dst[0]=t0_.x;  dst[1]=t0_.y;  dst[2]=t0_.z;  dst[3]=t0_.w;        \
        dst[4]=t1_.x;  dst[5]=t1_.y;  dst[6]=t1_.z;  dst[7]=t1_.w;        \
        dst[8]=t2_.x;  dst[9]=t2_.y;  dst[10]=t2_.z; dst[11]=t2_.w;       \
        dst[12]=t3_.x; dst[13]=t3_.y; dst[14]=t3_.z; dst[15]=t3_.w;       \
        dst[16]=t4_.x; dst[17]=t4_.y; dst[18]=t4_.z; dst[19]=t4_.w;       \
    }

    // ---- prologue: stage tile 0 (160 floats = 80 float2 per batch) ----
    float2 stage[5];
    #pragma unroll
    for (int i = 0; i < 5; ++i)
        stage[i] = *(const float2*)(xb + 2 * (l + 16 * i));

    int cur = 0;
    for (int tl = 0; tl < NTILE; ++tl) {
        // own-group LDS region, own wave: DS in-order per wave -> no barrier
        #pragma unroll
        for (int i = 0; i < 5; ++i)
            *(float2*)&lds_x[cur][g * XSTR + 2 * (l + 16 * i)] = stage[i];

        if (tl + 1 < NTILE) {
            const float* src = xb + (tl + 1) * (TILE * INn);
            #pragma unroll
            for (int i = 0; i < 5; ++i)
                stage[i] = *(const float2*)(src + 2 * (l + 16 * i));
        }

        const float4* xq = (const float4*)&lds_x[cur][g * XSTR];
        float xa[20], xbf[20];
        LOADX(xa, xq)                       // chunk 0
        const float4* pL = xq + 5;          // next chunk to load
        float* hw = hwb;                    // ring subchunk base

        // 4 dynamic iterations x 8 steps: ~4KB body (L1I-resident),
        // register double-buffer enforced by sched_barrier(0).
        for (int cc = 0; cc < 4; ++cc) {
            // even half: prefetch chunk 2cc+1 -> xbf, compute xa
            LOADX(xbf, pL)
            pL += 5;
            __builtin_amdgcn_sched_barrier(0);
            GRU_STEP(xa, 0, hw) GRU_STEP(xa, 1, hw)
            GRU_STEP(xa, 2, hw) GRU_STEP(xa, 3, hw)
            hw += 4;
            // odd half: prefetch chunk 2cc+2 -> xa, compute xbf.
            // cc==3 reads "chunk 8" past the 160-float slab: stays inside
            // the shared-memory allocation (slack + ring), values dead.
            LOADX(xa, pL)
            pL += 5;
            __builtin_amdgcn_sched_barrier(0);
            GRU_STEP(xbf, 0, hw) GRU_STEP(xbf, 1, hw)
            GRU_STEP(xbf, 2, hw) GRU_STEP(xbf, 3, hw)
            hw += 4;
        }

        // ---- flush head ring: output indices tl*32-1 .. tl*32+30 ----
        // (verified R12; guards skip the tl=0 pre-first outputs exactly)
        {
            float* omt = om + tl * 96 - 3;
            float* ort = orr + tl * 32 - 1;
            #pragma unroll
            for (int i = 0; i < 6; ++i) {
                float v = hrd[fq[i]];
                if (tl > 0 || i > 0 || l >= 3) omt[i * 16 + l] = v;
            }
            float v0 = hrd[102 + l];
            float v1 = hrd[102 + 16 + l];
            if (tl > 0 || l > 0) ort[l] = v0;
            ort[16 + l] = v1;
        }
        cur ^= 1;
    }

    // epilogue: head of final h (one more rotation), stored at index T-1
    {
        v2f accA = biasH;
        v2f accB = (v2f){0.0f, 0.0f};
        accA = pk_fma(whh_rot[0], splat2(hj), accA);
        accB = pk_fma(whh_rot[1], splat2(dppf<0x121>(hj)), accB);
        accA = pk_fma(whh_rot[2], splat2(dppf<0x122>(hj)), accA);
        accB = pk_fma(whh_rot[3], splat2(dppf<0x123>(hj)), accB);
        accA = pk_fma(whh_rot[4], splat2(dppf<0x124>(hj)), accA);
        accB = pk_fma(whh_rot[5], splat2(dppf<0x125>(hj)), accB);
        accA = pk_fma(whh_rot[6], splat2(dppf<0x126>(hj)), accA);
        accB = pk_fma(whh_rot[7], splat2(dppf<0x127>(hj)), accB);
        v2f accH = accA + accB;
        if (hl)  om[(Tn - 1) * 3 + (lo8 ? 0 : 2)] = accH[0];
        if (hl && lo8) om[(Tn - 1) * 3 + 1] = accH[1];
        if (is15)      orr[Tn - 1]          = accH[1];
    }

    // h_last: [1, B, H]
    if (l < Hn) out[OFF_HL + (long long)b * Hn + l] = hj;

    #undef GRU_STEP
    #undef LOADX
}

extern "C" void kernel_launch(void* const* d_in, const int* in_sizes, int n_in,
                              void* d_out, int out_size, void* d_ws, size_t ws_size,
                              hipStream_t stream) {
    const float* x    = (const float*)d_in[0];
    // d_in[1] = batch_size (scalar), unused — B compiled in
    const float* W_ih = (const float*)d_in[2];
    const float* W_hh = (const float*)d_in[3];
    const float* b_ih = (const float*)d_in[4];
    const float* b_hh = (const float*)d_in[5];
    const float* W_h0 = (const float*)d_in[6];
    const float* W_m  = (const float*)d_in[7];
    const float* b_m  = (const float*)d_in[8];
    const float* W_r  = (const float*)d_in[9];
    const float* b_r  = (const float*)d_in[10];
    float* out = (float*)d_out;

    dim3 grid(Bn / BPB);  // 512 blocks
    dim3 block(256);      // 16 batch elements x 16 lanes
    gru_fused_kernel<<<grid, block, 0, stream>>>(x, W_ih, W_hh, b_ih, b_hh,
                                                 W_h0, W_m, b_m, W_r, b_r, out);
}